// Round 4
// baseline (115.857 us; speedup 1.0000x reference)
//
#include <hip/hip_runtime.h>

#define N_ENT 100000
#define NB 16
#define DIM 128
#define TILE 64
#define RSTRIDE 132      // 128+4 floats: per-lane b128 reads conflict-free
#define N_TILES ((N_ENT + TILE - 1) / TILE)   // 1563

// Workspace in module statics (d_ws poison fills are unconditional — round-1
// A/B). Every slot written before read on every launch.
__device__ float g_partials[NB * N_TILES];    // 100 KB

// ---------------- kernel 1: fused head-norms + dist + exp -------------------
// Round-4: head_kernel deleted. Each block computes the 32 inverse norms
// (16 ent[e1[b]] rows + 16 rel[r[b]] rows, L2-hot after first blocks) at
// block start, and the main loop s_loads the RAW head rows (wave-uniform ->
// scalar cache) forming q = ev*iNe + rv*iNr on the fly (+16 VALU/j, still
// under the HBM ceiling). Saves one kernel launch + inter-kernel gap.
// Structure otherwise round-1 best: 8 waves x 2 b/wave, 4 blocks/CU = 100%.
__global__ __launch_bounds__(512, 8) void dist_kernel(
    const int* __restrict__ e1, const int* __restrict__ rel,
    const float* __restrict__ ent, const float* __restrict__ relemb,
    float* __restrict__ out)
{
    __shared__ float ldsRow[TILE * RSTRIDE];   // 33792 B
    __shared__ float ldsInv[TILE];             // 256 B (entity inv-norms)
    __shared__ float ldsHN[2 * NB];            // 128 B (head: iNe[16], iNr[16])

    const int tid  = threadIdx.x;
    const int lane = tid & 63;
    const int wv   = __builtin_amdgcn_readfirstlane(tid >> 6);  // uniform 0..7
    const int bbase = wv * 2;
    const int n0 = blockIdx.x * TILE;

    // ---- head norms: 32 rows x 16 threads x 8 floats, shfl_xor reduce ----
    {
        const int row = tid >> 4, q = tid & 15;          // row 0..31
        const float* base = (row < NB)
            ? (ent    + (size_t)e1[row] * DIM)
            : (relemb + (size_t)rel[row - NB] * DIM);
        float4 u0 = ((const float4*)base)[q * 2 + 0];
        float4 u1 = ((const float4*)base)[q * 2 + 1];
        float s = 0.f;
        s = fmaf(u0.x, u0.x, s); s = fmaf(u0.y, u0.y, s);
        s = fmaf(u0.z, u0.z, s); s = fmaf(u0.w, u0.w, s);
        s = fmaf(u1.x, u1.x, s); s = fmaf(u1.y, u1.y, s);
        s = fmaf(u1.z, u1.z, s); s = fmaf(u1.w, u1.w, s);
        s += __shfl_xor(s, 8); s += __shfl_xor(s, 4);
        s += __shfl_xor(s, 2); s += __shfl_xor(s, 1);
        if (q == 0) ldsHN[row] = 1.0f / fmaxf(sqrtf(s), 1e-12f);
    }

    // ---- stage entity rows AND compute entity norms in one pass ----------
    {
        const float4* eg = (const float4*)ent;
        const int r = tid >> 3, q = tid & 7;
        int gr = n0 + r;
        if (gr >= N_ENT) gr = N_ENT - 1;       // clamp for partial last tile
        const float4* grow = eg + gr * (DIM / 4);
        float s = 0.f;
        #pragma unroll
        for (int i = 0; i < 4; i++) {
            float4 v = grow[q + 8 * i];
            *(float4*)&ldsRow[r * RSTRIDE + (q + 8 * i) * 4] = v;
            s = fmaf(v.x, v.x, s); s = fmaf(v.y, v.y, s);
            s = fmaf(v.z, v.z, s); s = fmaf(v.w, v.w, s);
        }
        s += __shfl_down(s, 4);
        s += __shfl_down(s, 2);
        s += __shfl_down(s, 1);
        if (q == 0) ldsInv[r] = 1.0f / fmaxf(sqrtf(s), 1e-12f);
    }
    __syncthreads();

    const float inv = ldsInv[lane];
    // per-wave head-row pointers (wave-uniform -> scalar loads in the loop)
    const float4* E0 = (const float4*)(ent    + (size_t)e1[bbase + 0] * DIM);
    const float4* E1 = (const float4*)(ent    + (size_t)e1[bbase + 1] * DIM);
    const float4* R0 = (const float4*)(relemb + (size_t)rel[bbase + 0] * DIM);
    const float4* R1 = (const float4*)(relemb + (size_t)rel[bbase + 1] * DIM);
    const float iNe0 = ldsHN[bbase + 0],      iNe1 = ldsHN[bbase + 1];
    const float iNr0 = ldsHN[NB + bbase + 0], iNr1 = ldsHN[NB + bbase + 1];
    const float* rp = &ldsRow[lane * RSTRIDE];

    float a0 = 0.f, a1 = 0.f;
    #pragma unroll
    for (int j = 0; j < DIM / 4; j++) {
        float4 v  = *(const float4*)&rp[j * 4];
        float4 e0v = E0[j], e1v = E1[j];       // uniform -> s_load_dwordx4
        float4 r0v = R0[j], r1v = R1[j];
        float q0x = e0v.x * iNe0 + r0v.x * iNr0;
        float q0y = e0v.y * iNe0 + r0v.y * iNr0;
        float q0z = e0v.z * iNe0 + r0v.z * iNr0;
        float q0w = e0v.w * iNe0 + r0v.w * iNr0;
        float q1x = e1v.x * iNe1 + r1v.x * iNr1;
        float q1y = e1v.y * iNe1 + r1v.y * iNr1;
        float q1z = e1v.z * iNe1 + r1v.z * iNr1;
        float q1w = e1v.w * iNe1 + r1v.w * iNr1;
        a0 += fabsf(fmaf(-v.x, inv, q0x)) + fabsf(fmaf(-v.y, inv, q0y))
            + fabsf(fmaf(-v.z, inv, q0z)) + fabsf(fmaf(-v.w, inv, q0w));
        a1 += fabsf(fmaf(-v.x, inv, q1x)) + fabsf(fmaf(-v.y, inv, q1y))
            + fabsf(fmaf(-v.z, inv, q1z)) + fabsf(fmaf(-v.w, inv, q1w));
    }

    // exp; no max-subtract needed: dist <= 34, sums < 6e19 << fp32 max
    const int n = n0 + lane;
    const bool valid = (n < N_ENT);
    float e0 = valid ? __expf(a0) : 0.f;
    float e1x = valid ? __expf(a1) : 0.f;
    if (valid) {
        out[(bbase + 0) * N_ENT + n] = e0;     // lane-contiguous: coalesced
        out[(bbase + 1) * N_ENT + n] = e1x;
    }

#define WRED(x) { x += __shfl_down(x, 32); x += __shfl_down(x, 16); \
                  x += __shfl_down(x, 8);  x += __shfl_down(x, 4);  \
                  x += __shfl_down(x, 2);  x += __shfl_down(x, 1); }
    WRED(e0) WRED(e1x)
#undef WRED
    if (lane == 0) {   // b-major: partials[b*N_TILES + block] — no contention
        g_partials[(bbase + 0) * N_TILES + blockIdx.x] = e0;
        g_partials[(bbase + 1) * N_TILES + blockIdx.x] = e1x;
    }
}

// ---------------- kernel 2: out *= 1/sum(partials[b][*]) --------------------
// Each block redundantly reduces its row's 1563 partials (6.3 KB, L2-hot).
__global__ __launch_bounds__(256) void scale_kernel(float* __restrict__ out)
{
    const int b = blockIdx.y;
    const int tid = threadIdx.x;

    // load my output chunk first (overlaps with the reduction)
    const int i = blockIdx.x * 256 + tid;              // float4 index
    float4 v = make_float4(0.f, 0.f, 0.f, 0.f);
    float4* row = (float4*)&out[b * N_ENT];
    const bool valid = (i < N_ENT / 4);
    if (valid) v = row[i];

    float s = 0.f;
    for (int k = tid; k < N_TILES; k += 256) s += g_partials[b * N_TILES + k];
    s += __shfl_down(s, 32); s += __shfl_down(s, 16);
    s += __shfl_down(s, 8);  s += __shfl_down(s, 4);
    s += __shfl_down(s, 2);  s += __shfl_down(s, 1);
    __shared__ float red[4];
    if ((tid & 63) == 0) red[tid >> 6] = s;
    __syncthreads();
    const float invS = 1.0f / (red[0] + red[1] + red[2] + red[3]);

    if (valid) {
        v.x *= invS; v.y *= invS; v.z *= invS; v.w *= invS;
        row[i] = v;
    }
}

extern "C" void kernel_launch(void* const* d_in, const int* in_sizes, int n_in,
                              void* d_out, int out_size, void* d_ws, size_t ws_size,
                              hipStream_t stream) {
    const int*   e1     = (const int*)d_in[0];
    const int*   rel    = (const int*)d_in[1];
    const float* ent    = (const float*)d_in[4];
    const float* relemb = (const float*)d_in[5];
    float* out = (float*)d_out;
    (void)d_ws; (void)ws_size;

    dist_kernel<<<N_TILES, 512, 0, stream>>>(e1, rel, ent, relemb, out);
    scale_kernel<<<dim3((N_ENT / 4 + 255) / 256, NB), 256, 0, stream>>>(out);
}

// Round 5
// 108.905 us; speedup vs baseline: 1.0638x; 1.0638x over previous
//
#include <hip/hip_runtime.h>

#define N_ENT 100000
#define NB 16
#define DIM 128
#define TILE 64
#define RSTRIDE 132      // 128+4 floats: per-lane b128 reads conflict-free
#define N_TILES ((N_ENT + TILE - 1) / TILE)   // 1563

// Workspace in module statics (d_ws poison fills are unconditional — round-1
// A/B). Every slot written before read on every launch.
// REVERT to round-3 best (109.0 us): round-4's head-fusion into dist
// regressed (+6.9 us — 16 extra VALU/j + scalar-load lgkmcnt serialization
// + 25 MB redundant head-row reads beat the ~2 us launch saving).
__device__ float g_head[NB * DIM];            // 8 KB
__device__ float g_partials[NB * N_TILES];    // 100 KB

// ---------------- kernel 1: head = normalize(ent[e1]) + normalize(rel[r]) ----
__global__ __launch_bounds__(128) void head_kernel(
    const int* __restrict__ e1, const int* __restrict__ rel,
    const float* __restrict__ ent, const float* __restrict__ relemb)
{
    int b = blockIdx.x, d = threadIdx.x;
    float ev = ent[e1[b] * DIM + d];
    float rv = relemb[rel[b] * DIM + d];
    __shared__ float s1[DIM], s2[DIM];
    s1[d] = ev * ev;
    s2[d] = rv * rv;
    __syncthreads();
    for (int s = 64; s > 0; s >>= 1) {
        if (d < s) { s1[d] += s1[d + s]; s2[d] += s2[d + s]; }
        __syncthreads();
    }
    float ne = fmaxf(sqrtf(s1[0]), 1e-12f);
    float nr = fmaxf(sqrtf(s2[0]), 1e-12f);
    g_head[b * DIM + d] = ev / ne + rv / nr;
}

// ---------------- kernel 2: fused dist + exp; 8 waves/block, 2 b per wave ---
// Best-measured structure (109.0 us): 1563 blocks, one 64-entity tile each.
// Block = 512 thr = 8 waves; wave w computes b in [2w,2w+2) for all 64
// entities (lane = entity). LDS 34 KB -> 4 blocks/CU = 32 waves/CU = 100%
// occupancy. Norm computation fused into staging (each thread loads 4 float4
// of the SAME row, sq-accumulates in-register, 8-lane shfl reduce) — saves
// the 64-instr/block LDS norm re-read pass and one barrier.
__global__ __launch_bounds__(512, 8) void dist_kernel(
    const float* __restrict__ ent, float* __restrict__ out)
{
    __shared__ float ldsRow[TILE * RSTRIDE];   // 33792 B
    __shared__ float ldsInv[TILE];             // 256 B

    const int tid  = threadIdx.x;
    const int lane = tid & 63;
    const int wv   = __builtin_amdgcn_readfirstlane(tid >> 6);  // uniform 0..7
    const int bbase = wv * 2;
    const int n0 = blockIdx.x * TILE;
    const float4* __restrict__ hg = (const float4*)g_head;  // uniform-indexed

    // stage rows AND compute norms in one pass:
    // thread t owns row r = t>>3, eighth q = t&7; loads float4 cols
    // q, q+8, q+16, q+24. Per instr a wave touches 8 rows x 128B contiguous
    // = 16 cache lines for 1 KB -> fully coalesced. Sq-sum stays in regs.
    {
        const float4* eg = (const float4*)ent;
        const int r = tid >> 3, q = tid & 7;
        int gr = n0 + r;
        if (gr >= N_ENT) gr = N_ENT - 1;       // clamp for partial last tile
        const float4* grow = eg + gr * (DIM / 4);
        float s = 0.f;
        #pragma unroll
        for (int i = 0; i < 4; i++) {
            float4 v = grow[q + 8 * i];
            *(float4*)&ldsRow[r * RSTRIDE + (q + 8 * i) * 4] = v;
            s = fmaf(v.x, v.x, s); s = fmaf(v.y, v.y, s);
            s = fmaf(v.z, v.z, s); s = fmaf(v.w, v.w, s);
        }
        s += __shfl_down(s, 4);
        s += __shfl_down(s, 2);
        s += __shfl_down(s, 1);
        if (q == 0) ldsInv[r] = 1.0f / fmaxf(sqrtf(s), 1e-12f);
    }
    __syncthreads();

    const float inv = ldsInv[lane];
    const float* rp = &ldsRow[lane * RSTRIDE];

    float a0 = 0.f, a1 = 0.f;
    #pragma unroll
    for (int j = 0; j < DIM / 4; j++) {
        float4 v  = *(const float4*)&rp[j * 4];
        float4 q0 = hg[(bbase + 0) * (DIM / 4) + j];   // uniform -> s_load
        float4 q1 = hg[(bbase + 1) * (DIM / 4) + j];
        a0 += fabsf(fmaf(-v.x, inv, q0.x)) + fabsf(fmaf(-v.y, inv, q0.y))
            + fabsf(fmaf(-v.z, inv, q0.z)) + fabsf(fmaf(-v.w, inv, q0.w));
        a1 += fabsf(fmaf(-v.x, inv, q1.x)) + fabsf(fmaf(-v.y, inv, q1.y))
            + fabsf(fmaf(-v.z, inv, q1.z)) + fabsf(fmaf(-v.w, inv, q1.w));
    }

    // exp; no max-subtract needed: dist <= 34, sums < 6e19 << fp32 max
    const int n = n0 + lane;
    const bool valid = (n < N_ENT);
    float e0 = valid ? __expf(a0) : 0.f;
    float e1 = valid ? __expf(a1) : 0.f;
    if (valid) {
        out[(bbase + 0) * N_ENT + n] = e0;     // lane-contiguous: coalesced
        out[(bbase + 1) * N_ENT + n] = e1;
    }

#define WRED(x) { x += __shfl_down(x, 32); x += __shfl_down(x, 16); \
                  x += __shfl_down(x, 8);  x += __shfl_down(x, 4);  \
                  x += __shfl_down(x, 2);  x += __shfl_down(x, 1); }
    WRED(e0) WRED(e1)
#undef WRED
    if (lane == 0) {   // b-major: partials[b*N_TILES + block] — no contention
        g_partials[(bbase + 0) * N_TILES + blockIdx.x] = e0;
        g_partials[(bbase + 1) * N_TILES + blockIdx.x] = e1;
    }
}

// ---------------- kernel 3: out *= 1/sum(partials[b][*]) --------------------
// Each block redundantly reduces its row's 1563 partials (6.3 KB, L2-hot).
__global__ __launch_bounds__(256) void scale_kernel(float* __restrict__ out)
{
    const int b = blockIdx.y;
    const int tid = threadIdx.x;

    // load my output chunk first (overlaps with the reduction)
    const int i = blockIdx.x * 256 + tid;              // float4 index
    float4 v = make_float4(0.f, 0.f, 0.f, 0.f);
    float4* row = (float4*)&out[b * N_ENT];
    const bool valid = (i < N_ENT / 4);
    if (valid) v = row[i];

    float s = 0.f;
    for (int k = tid; k < N_TILES; k += 256) s += g_partials[b * N_TILES + k];
    s += __shfl_down(s, 32); s += __shfl_down(s, 16);
    s += __shfl_down(s, 8);  s += __shfl_down(s, 4);
    s += __shfl_down(s, 2);  s += __shfl_down(s, 1);
    __shared__ float red[4];
    if ((tid & 63) == 0) red[tid >> 6] = s;
    __syncthreads();
    const float invS = 1.0f / (red[0] + red[1] + red[2] + red[3]);

    if (valid) {
        v.x *= invS; v.y *= invS; v.z *= invS; v.w *= invS;
        row[i] = v;
    }
}

extern "C" void kernel_launch(void* const* d_in, const int* in_sizes, int n_in,
                              void* d_out, int out_size, void* d_ws, size_t ws_size,
                              hipStream_t stream) {
    const int*   e1     = (const int*)d_in[0];
    const int*   rel    = (const int*)d_in[1];
    const float* ent    = (const float*)d_in[4];
    const float* relemb = (const float*)d_in[5];
    float* out = (float*)d_out;
    (void)d_ws; (void)ws_size;

    head_kernel<<<16, 128, 0, stream>>>(e1, rel, ent, relemb);
    dist_kernel<<<N_TILES, 512, 0, stream>>>(ent, out);
    scale_kernel<<<dim3((N_ENT / 4 + 255) / 256, NB), 256, 0, stream>>>(out);
}